// Round 12
// baseline (1062.649 us; speedup 1.0000x reference)
//
#include <hip/hip_runtime.h>
#include <hip/hip_fp16.h>

#define TT 1024
#define BB 256
#define II 128
#define HH 256

typedef _Float16 f16x8 __attribute__((ext_vector_type(8)));
typedef float    f32x4 __attribute__((ext_vector_type(4)));

union HU { _Float16 h[2]; unsigned u; };
static __device__ __forceinline__ unsigned pack2f(float a, float b)
{
    HU t; t.h[0] = (_Float16)a; t.h[1] = (_Float16)b; return t.u;
}

// LDS-only barrier (global stores/loads stay in flight across steps).
#define LDS_BARRIER()                                            \
    do {                                                         \
        asm volatile("s_waitcnt lgkmcnt(0)" ::: "memory");       \
        __builtin_amdgcn_s_barrier();                            \
        __builtin_amdgcn_sched_barrier(0);                       \
    } while (0)

__device__ __forceinline__ float fast_tanh(float a)
{
    float e = __builtin_amdgcn_exp2f(a * 2.8853900817779268f);
    return 1.0f - 2.0f * __builtin_amdgcn_rcpf(e + 1.0f);
}

static __device__ __forceinline__ f16x8 cvt8(const float* p)
{
    float4 a = *(const float4*)p;
    float4 b = *(const float4*)(p + 4);
    f16x8 r;
    r[0]=(_Float16)a.x; r[1]=(_Float16)a.y; r[2]=(_Float16)a.z; r[3]=(_Float16)a.w;
    r[4]=(_Float16)b.x; r[5]=(_Float16)b.y; r[6]=(_Float16)b.z; r[7]=(_Float16)b.w;
    return r;
}

// ---------------- Pre-GEMM: xw = x @ W^T (fp32 into seq region) — unchanged (passed R10)
__global__ __launch_bounds__(256, 1)
void xw_gemm(const float* __restrict__ x, const float* __restrict__ W,
             float* __restrict__ xw)
{
    __shared__ _Float16 Wl[HH * II];
    const int tid  = threadIdx.x;
    const int l    = tid & 63;
    const int wv   = (__builtin_amdgcn_readfirstlane(tid) >> 6) & 3;
    const int lr   = l & 15;
    const int kgrp = l >> 4;

    {
        const int row = tid;
        const float4* src = (const float4*)(W + (size_t)row * II);
        unsigned* dst = (unsigned*)Wl;
        const int sw = (row & 7) << 4;
#pragma unroll
        for (int q = 0; q < II / 4; ++q) {
            float4 v = src[q];
            dst[(row * 256 + ((q * 8) ^ sw)) >> 2]     = pack2f(v.x, v.y);
            dst[(row * 256 + ((q * 8 + 4) ^ sw)) >> 2] = pack2f(v.z, v.w);
        }
    }
    __syncthreads();

    const size_t Mbase = (size_t)blockIdx.x * 64;
    const size_t arow  = Mbase + 16 * wv + lr;

    f16x8 afr[4];
#pragma unroll
    for (int kc = 0; kc < 4; ++kc)
        afr[kc] = cvt8(x + arow * II + kc * 32 + kgrp * 8);

    f32x4 acc[16];
#pragma unroll
    for (int nt = 0; nt < 16; ++nt) acc[nt] = f32x4{0.f, 0.f, 0.f, 0.f};

#pragma unroll
    for (int nt = 0; nt < 16; ++nt) {
        const int col = nt * 16 + lr;
        const int sw  = (col & 7) << 4;
#pragma unroll
        for (int kc = 0; kc < 4; ++kc) {
            f16x8 bfr = *(const f16x8*)((const char*)Wl + col * 256 +
                                        ((kc * 64 + kgrp * 16) ^ sw));
            acc[nt] = __builtin_amdgcn_mfma_f32_16x16x32_f16(afr[kc], bfr, acc[nt], 0, 0, 0);
        }
    }
#pragma unroll
    for (int nt = 0; nt < 16; ++nt) {
#pragma unroll
        for (int r = 0; r < 4; ++r) {
            size_t row = Mbase + 16 * wv + kgrp * 4 + r;
            xw[row * HH + nt * 16 + lr] = acc[nt][r];
        }
    }
}

// ---------------- Recurrence, operand-swapped: D = V (A, M=cols) x h^T (B, N=batch)
// 16 WGs x 16 REAL batch rows; 8 waves own 32 output cols each.
// C-layout: lane&15 = batch row, regs = 4 contiguous cols -> float4 epilogue on
// ALL 64 lanes, b64 LDS h-writes. h LDS layout rotated: slot=(k>>3 + 4*row)&31
// -> 2-way (free) on both ds_read_b128 and ds_write_b64. xw loads issued after
// the consuming buffer's last use -> 2-step prefetch distance.
__global__ __launch_bounds__(512, 1)
void rnn_mfma2(const float* __restrict__ bW, const float* __restrict__ V,
               const float* __restrict__ bV, float* __restrict__ out)
{
    __shared__ _Float16 hb[2][16 * HH];  // 2 x 8 KB
    const int tid   = threadIdx.x;
    const int l     = tid & 63;
    const int wv    = (__builtin_amdgcn_readfirstlane(tid) >> 6) & 7;
    const int lr    = l & 15;   // batch row (B-frag col, C col)
    const int kg    = l >> 4;   // k-subgroup
    const int brow0 = blockIdx.x * 16;

    // A-fragments: V[row = output col][k], lane holds V[col0+lr][kc*32+kg*8..+7]
    f16x8 vfr[2][8];
    f32x4 biasc[2];
#pragma unroll
    for (int nt = 0; nt < 2; ++nt) {
        const int col0 = wv * 32 + nt * 16;
#pragma unroll
        for (int kc = 0; kc < 8; ++kc)
            vfr[nt][kc] = cvt8(V + (size_t)(col0 + lr) * HH + kc * 32 + kg * 8);
        float4 b1 = *(const float4*)(bW + col0 + 4 * kg);
        float4 b2 = *(const float4*)(bV + col0 + 4 * kg);
        biasc[nt] = f32x4{b1.x + b2.x, b1.y + b2.y, b1.z + b2.z, b1.w + b2.w};
    }

    // Zero both h buffers (h(-1) = 0).
    {
        unsigned* hz = (unsigned*)hb;
#pragma unroll
        for (int q = 0; q < 8; ++q) hz[tid + q * 512] = 0u;
    }
    __syncthreads();

    // Rotated-layout addresses. Read: lane(lr=row, kg) reads h[lr][kc*32+kg*8..+7].
    int raddr[8];
#pragma unroll
    for (int kc = 0; kc < 8; ++kc)
        raddr[kc] = lr * 512 + (((4 * kc + kg + 4 * lr) & 31) << 4);
    // Write: lane(lr=row, kg) writes h[lr][wv*32+nt*16+4kg .. +3] as b64.
    int waddr[2];
#pragma unroll
    for (int nt = 0; nt < 2; ++nt)
        waddr[nt] = lr * 512 + (((4 * wv + 2 * nt + (kg >> 1) + 4 * lr) & 31) << 4)
                  + 8 * (kg & 1);

    float* __restrict__ seq = out;
    float* __restrict__ fin = out + (size_t)TT * BB * HH;

    const size_t rowstr = HH;
    const int colA = wv * 32 + 4 * kg;        // nt=0 col base for xw/seq/fin
    const int colB = wv * 32 + 16 + 4 * kg;   // nt=1

    // xw pipeline: XA = xw[0], XB = xw[1].
    f32x4 XA0, XA1, XB0, XB1;
    XA0 = *(const f32x4*)(seq + ((size_t)0 * BB + brow0 + lr) * rowstr + colA);
    XA1 = *(const f32x4*)(seq + ((size_t)0 * BB + brow0 + lr) * rowstr + colB);
    XB0 = *(const f32x4*)(seq + ((size_t)1 * BB + brow0 + lr) * rowstr + colA);
    XB1 = *(const f32x4*)(seq + ((size_t)1 * BB + brow0 + lr) * rowstr + colB);

#define STEP(CUR, NXT, X0, X1, T)                                               \
    {                                                                           \
        const char* hbase = (const char*)&hb[CUR][0];                           \
        f16x8 hfr[8];                                                           \
        _Pragma("unroll")                                                       \
        for (int kc = 0; kc < 8; ++kc)                                          \
            hfr[kc] = *(const f16x8*)(hbase + raddr[kc]);                       \
        f32x4 acc0 = f32x4{0.f,0.f,0.f,0.f}, acc1 = f32x4{0.f,0.f,0.f,0.f};     \
        _Pragma("unroll")                                                       \
        for (int kc = 0; kc < 8; ++kc) {                                        \
            acc0 = __builtin_amdgcn_mfma_f32_16x16x32_f16(vfr[0][kc], hfr[kc], acc0, 0, 0, 0); \
            acc1 = __builtin_amdgcn_mfma_f32_16x16x32_f16(vfr[1][kc], hfr[kc], acc1, 0, 0, 0); \
        }                                                                       \
        char* wbase = (char*)&hb[NXT][0];                                       \
        f32x4 hv0, hv1;                                                         \
        _Pragma("unroll")                                                       \
        for (int r = 0; r < 4; ++r) hv0[r] = fast_tanh(acc0[r] + X0[r] + biasc[0][r]); \
        _Pragma("unroll")                                                       \
        for (int r = 0; r < 4; ++r) hv1[r] = fast_tanh(acc1[r] + X1[r] + biasc[1][r]); \
        float* srow = seq + ((size_t)(T) * BB + brow0 + lr) * rowstr;           \
        *(f32x4*)(srow + colA) = hv0;                                           \
        *(f32x4*)(srow + colB) = hv1;                                           \
        if ((T) == TT - 1) {                                                    \
            float* frow = fin + (size_t)(brow0 + lr) * rowstr;                  \
            *(f32x4*)(frow + colA) = hv0;                                       \
            *(f32x4*)(frow + colB) = hv1;                                       \
        }                                                                       \
        uint2 w0; w0.x = pack2f(hv0[0], hv0[1]); w0.y = pack2f(hv0[2], hv0[3]); \
        uint2 w1; w1.x = pack2f(hv1[0], hv1[1]); w1.y = pack2f(hv1[2], hv1[3]); \
        *(uint2*)(wbase + waddr[0]) = w0;                                       \
        *(uint2*)(wbase + waddr[1]) = w1;                                       \
        /* refill X (consumed above) with xw[T+2]: 2-step prefetch distance */  \
        {                                                                       \
            int tp = ((T) + 2 < TT) ? (T) + 2 : (T);                            \
            const float* prow = seq + ((size_t)tp * BB + brow0 + lr) * rowstr;  \
            X0 = *(const f32x4*)(prow + colA);                                  \
            X1 = *(const f32x4*)(prow + colB);                                  \
        }                                                                       \
        LDS_BARRIER();                                                          \
    }

#pragma unroll 1
    for (int t = 0; t < TT; t += 2) {
        STEP(0, 1, XA0, XA1, t);
        STEP(1, 0, XB0, XB1, t + 1);
    }
#undef STEP
}

extern "C" void kernel_launch(void* const* d_in, const int* in_sizes, int n_in,
                              void* d_out, int out_size, void* d_ws, size_t ws_size,
                              hipStream_t stream)
{
    const float* x  = (const float*)d_in[0];
    const float* W  = (const float*)d_in[1];
    const float* bW = (const float*)d_in[2];
    const float* V  = (const float*)d_in[3];
    const float* bV = (const float*)d_in[4];
    float* out = (float*)d_out;

    xw_gemm<<<dim3((TT * BB) / 64), dim3(256), 0, stream>>>(x, W, out);
    rnn_mfma2<<<dim3(BB / 16), dim3(512), 0, stream>>>(bW, V, bV, out);
}